// Round 8
// baseline (1563.490 us; speedup 1.0000x reference)
//
#include <hip/hip_runtime.h>
#include <cstdint>

// ---------------------------------------------------------------------------
// GCN Siamese. Class-major binning -> reorder to node-major CSR ->
// 4-node-per-wave (16 lanes/row, ushort4) gather aggregation.
//   per branch:
//     k_bcnt : count per (class=blockIdx&7, dst)  [bcnt[c*N+d]]
//     k_deg  : degN, dinv, rowstart[N]=E
//     scanA/B/C (bcnt[8N])  -> cur   (class-major claim bases)
//     scanA/B/C (degN[N])   -> rowstart (node-major CSR)
//     k_bin  : class-major claim+write col        (after: cur = segment ends)
//     k_reorder: col (class-major) -> colN (node-major rows)
//     k_mm<128>: XWs = bf16(dinv * (X@W1))
//     k_agg4<false>: wave = 4 nodes (16-lane groups), unroll-8 row gathers
//     k_mm<64> : XWs = bf16(dinv * (H1@W2))
//     k_agg4<true>: same, epilogue pools into emb/cnt
//   head: sigmoid(relu([e1,e2,|e1-e2|]@fc1+b)@fc2+b)
// N=100000, E=3.2M, G=1024
// ---------------------------------------------------------------------------

__device__ __forceinline__ float fatomic(float* p, float v) {
    return unsafeAtomicAdd(p, v);   // hw global_atomic_add_f32
}
__device__ __forceinline__ float bf2f(unsigned short u) {
    union { unsigned int i; float f; } c; c.i = ((unsigned int)u) << 16; return c.f;
}
__device__ __forceinline__ unsigned short f2bf(float f) {
    union { float f; unsigned int i; } c; c.f = f;
    const unsigned int b = c.i;
    return (unsigned short)((b + 0x7FFF + ((b >> 16) & 1)) >> 16);   // RNE
}

// count per (class, dst node); class = blockIdx&7 (XCD round-robin)
__global__ void k_bcnt(const int* __restrict__ dst, int* __restrict__ bcnt,
                       int E4, int E, int Nn) {
    int i = blockIdx.x * blockDim.x + threadIdx.x;
    const int base = (blockIdx.x & 7) * Nn;
    const int stride = gridDim.x * blockDim.x;
    for (; i < E4; i += stride) {
        const int4 d = ((const int4*)dst)[i];
        atomicAdd(&bcnt[base + d.x], 1);
        atomicAdd(&bcnt[base + d.y], 1);
        atomicAdd(&bcnt[base + d.z], 1);
        atomicAdd(&bcnt[base + d.w], 1);
    }
    if (blockIdx.x == 0) {       // tail, class 0 (must match k_bin)
        const int t0 = E4 * 4;
        const int tl = E - t0;
        if ((int)threadIdx.x < tl) atomicAdd(&bcnt[dst[t0 + threadIdx.x]], 1);
    }
}

// degN[i], dinv[i]; rowstart[N] = E
__global__ __launch_bounds__(256) void k_deg(const int* __restrict__ bcnt,
                                             int* __restrict__ degN,
                                             float* __restrict__ dinv,
                                             int* __restrict__ rowstart,
                                             int Nn, int E) {
    const int i = blockIdx.x * 256 + threadIdx.x;
    if (i == 0) rowstart[Nn] = E;
    if (i >= Nn) return;
    int d = 0;
#pragma unroll
    for (int c = 0; c < 8; ++c) d += bcnt[c * Nn + i];
    degN[i] = d;
    dinv[i] = rsqrtf((float)d + 1.0f);
}

// ---- generic flat hierarchical exclusive scan (M ints, M%4==0) ------------
__global__ __launch_bounds__(256) void k_scanA(const int* __restrict__ in,
                                               int* __restrict__ partial, int M4) {
    __shared__ int sm[256];
    const int t = threadIdx.x;
    const int i4 = blockIdx.x * 256 + t;
    int s = 0;
    if (i4 < M4) {
        const int4 v = ((const int4*)in)[i4];
        s = (v.x + v.y) + (v.z + v.w);
    }
    sm[t] = s;
    __syncthreads();
    for (int off = 128; off > 0; off >>= 1) {
        if (t < off) sm[t] += sm[t + off];
        __syncthreads();
    }
    if (t == 0) partial[blockIdx.x] = sm[0];
}

__global__ __launch_bounds__(1024) void k_scanB(int* __restrict__ partial, int NBLK) {
    __shared__ int sm[1024];
    const int t = threadIdx.x;
    const int v = (t < NBLK) ? partial[t] : 0;
    sm[t] = v;
    __syncthreads();
    for (int off = 1; off < 1024; off <<= 1) {
        const int u = (t >= off) ? sm[t - off] : 0;
        __syncthreads();
        sm[t] += u;
        __syncthreads();
    }
    if (t < NBLK) partial[t] = sm[t] - v;   // exclusive
}

__global__ __launch_bounds__(256) void k_scanC(const int* __restrict__ in,
                                               const int* __restrict__ partial,
                                               int* __restrict__ outbase, int M4) {
    __shared__ int sm[256];
    const int t = threadIdx.x;
    const int i4 = blockIdx.x * 256 + t;
    int4 v = make_int4(0, 0, 0, 0);
    if (i4 < M4) v = ((const int4*)in)[i4];
    const int s = (v.x + v.y) + (v.z + v.w);
    sm[t] = s;
    __syncthreads();
    for (int off = 1; off < 256; off <<= 1) {
        const int u = (t >= off) ? sm[t - off] : 0;
        __syncthreads();
        sm[t] += u;
        __syncthreads();
    }
    if (i4 < M4) {
        int run = partial[blockIdx.x] + sm[t] - s;
        int4 w;
        w.x = run;
        w.y = w.x + v.x;
        w.z = w.y + v.y;
        w.w = w.z + v.z;
        ((int4*)outbase)[i4] = w;
    }
}

// claim + write col[pos] = src (class-major). Same mapping as k_bcnt.
__global__ void k_bin(const int* __restrict__ src, const int* __restrict__ dst,
                      int* __restrict__ cur, int* __restrict__ col,
                      int E4, int E, int Nn) {
    int i = blockIdx.x * blockDim.x + threadIdx.x;
    const int base = (blockIdx.x & 7) * Nn;
    const int stride = gridDim.x * blockDim.x;
    for (; i < E4; i += stride) {
        const int4 d = ((const int4*)dst)[i];
        const int4 sv = ((const int4*)src)[i];
        int p;
        p = atomicAdd(&cur[base + d.x], 1); col[p] = sv.x;
        p = atomicAdd(&cur[base + d.y], 1); col[p] = sv.y;
        p = atomicAdd(&cur[base + d.z], 1); col[p] = sv.z;
        p = atomicAdd(&cur[base + d.w], 1); col[p] = sv.w;
    }
    if (blockIdx.x == 0) {
        const int t0 = E4 * 4;
        const int tl = E - t0;
        if ((int)threadIdx.x < tl) {
            const int e = t0 + threadIdx.x;
            const int p = atomicAdd(&cur[dst[e]], 1);
            col[p] = src[e];
        }
    }
}

// class-major col -> node-major colN. Thread = (node i = tid>>3, class c = tid&7).
__global__ __launch_bounds__(256) void k_reorder(const int* __restrict__ col,
                                                 const int* __restrict__ cur,
                                                 const int* __restrict__ bcnt,
                                                 const int* __restrict__ rowstart,
                                                 int* __restrict__ colN, int Nn) {
    const int tid = blockIdx.x * 256 + threadIdx.x;
    if (tid >= Nn * 8) return;
    const int i = tid >> 3;
    const int c = tid & 7;
    const int L = bcnt[c * Nn + i];
    int pref = L;
#pragma unroll
    for (int d = 1; d < 8; d <<= 1) {
        const int u = __shfl_up(pref, d, 8);
        if (c >= d) pref += u;
    }
    const int off = rowstart[i] + (pref - L);
    if (L == 0) return;
    const int s0 = cur[c * Nn + i] - L;     // class-major segment start
    for (int k = 0; k < L; ++k)
        colN[off + k] = col[s0 + k];
}

// Y[row] = bf16(dinv[row] * (X@W)[row]) ; X is f32 or bf16
template <int K, bool BF16IN>
__global__ __launch_bounds__(256) void k_mm(const void* __restrict__ Xv,
                                            const float* __restrict__ W,
                                            const float* __restrict__ dinv,
                                            unsigned short* __restrict__ Y, int n) {
    __shared__ float WL[K * 64];
    __shared__ float XT[32 * K];
    const int tid = threadIdx.x;
    for (int i = tid * 4; i < K * 64; i += 1024)
        *(float4*)&WL[i] = *(const float4*)&W[i];
    const int rowBase = blockIdx.x * 32;
    const int rows = min(32, n - rowBase);
    if (BF16IN) {
        const unsigned short* xs = (const unsigned short*)Xv + (size_t)rowBase * K;
        for (int i = tid * 4; i < rows * K; i += 1024) {
            const ushort4 u = *(const ushort4*)&xs[i];
            XT[i + 0] = bf2f(u.x); XT[i + 1] = bf2f(u.y);
            XT[i + 2] = bf2f(u.z); XT[i + 3] = bf2f(u.w);
        }
    } else {
        const float* xs = (const float*)Xv + (size_t)rowBase * K;
        for (int i = tid * 4; i < rows * K; i += 1024)
            *(float4*)&XT[i] = *(const float4*)&xs[i];
    }
    __syncthreads();
    const int colf = tid & 63;
    const int rg = tid >> 6;
    float acc[8] = {};
    for (int k4 = 0; k4 < K / 4; ++k4) {
        const float w0 = WL[(k4 * 4 + 0) * 64 + colf];
        const float w1 = WL[(k4 * 4 + 1) * 64 + colf];
        const float w2 = WL[(k4 * 4 + 2) * 64 + colf];
        const float w3 = WL[(k4 * 4 + 3) * 64 + colf];
#pragma unroll
        for (int r = 0; r < 8; ++r) {
            const float4 xv = *(const float4*)&XT[(rg * 8 + r) * K + k4 * 4];
            acc[r] += xv.x * w0 + xv.y * w1 + xv.z * w2 + xv.w * w3;
        }
    }
#pragma unroll
    for (int r = 0; r < 8; ++r) {
        const int row = rowBase + rg * 8 + r;
        if (row < n) Y[(size_t)row * 64 + colf] = f2bf(dinv[row] * acc[r]);
    }
}

// node-major CSR aggregation: 16 lanes per node row (ushort4 = 4 feats/lane),
// 4 nodes per wave concurrently, unroll-8 -> up to 64 rows in flight per wave.
template <bool POOL>
__global__ __launch_bounds__(256) void k_agg4(const int* __restrict__ colN,
                                              const int* __restrict__ rowstart,
                                              const float* __restrict__ dinv,
                                              const ushort4* __restrict__ XW4,
                                              const float4* __restrict__ bias4,
                                              ushort4* __restrict__ H4,
                                              const int* __restrict__ batch,
                                              float* __restrict__ emb,
                                              float* __restrict__ cnt, int Nn) {
    const int lane = threadIdx.x & 63;
    const int grp = lane >> 4;          // group 0..3 -> node
    const int l16 = lane & 15;          // feature quad
    const int wid = (blockIdx.x * blockDim.x + threadIdx.x) >> 6;
    const int nw = (gridDim.x * blockDim.x) >> 6;
    const float4 bl = bias4[l16];
    for (int nb = wid * 4; nb < Nn; nb += nw * 4) {
        const int i = nb + grp;
        int s = 0, e = 0;
        if (i < Nn) { s = rowstart[i]; e = rowstart[i + 1]; }
        float a0 = 0.f, a1 = 0.f, a2 = 0.f, a3 = 0.f;
        int j = s;
        for (; j + 8 <= e; j += 8) {        // group-uniform bound (exec-masked)
            int idx[8];
#pragma unroll
            for (int q = 0; q < 8; ++q) idx[q] = colN[j + q];   // 16-lane broadcast
            ushort4 r[8];
#pragma unroll
            for (int q = 0; q < 8; ++q) r[q] = XW4[(size_t)idx[q] * 16 + l16];
#pragma unroll
            for (int q = 0; q < 8; ++q) {
                a0 += bf2f(r[q].x); a1 += bf2f(r[q].y);
                a2 += bf2f(r[q].z); a3 += bf2f(r[q].w);
            }
        }
        for (; j < e; ++j) {
            const ushort4 r = XW4[(size_t)colN[j] * 16 + l16];
            a0 += bf2f(r.x); a1 += bf2f(r.y); a2 += bf2f(r.z); a3 += bf2f(r.w);
        }
        if (i < Nn) {
            const float di = dinv[i];
            const ushort4 sf = XW4[(size_t)i * 16 + l16];
            const float v0 = fmaxf(di * (a0 + bf2f(sf.x)) + bl.x, 0.0f);
            const float v1 = fmaxf(di * (a1 + bf2f(sf.y)) + bl.y, 0.0f);
            const float v2 = fmaxf(di * (a2 + bf2f(sf.z)) + bl.z, 0.0f);
            const float v3 = fmaxf(di * (a3 + bf2f(sf.w)) + bl.w, 0.0f);
            if (POOL) {
                const int g = batch[i];
                float* ep = &emb[(size_t)g * 64 + l16 * 4];
                fatomic(ep + 0, v0); fatomic(ep + 1, v1);
                fatomic(ep + 2, v2); fatomic(ep + 3, v3);
                if (l16 == 0) fatomic(&cnt[g], 1.0f);
            } else {
                ushort4 o;
                o.x = f2bf(v0); o.y = f2bf(v1); o.z = f2bf(v2); o.w = f2bf(v3);
                H4[(size_t)i * 16 + l16] = o;
            }
        }
    }
}

// head: emb -> [e1,e2,|e1-e2|] @ fc1 -> relu -> @ fc2 -> sigmoid
__global__ __launch_bounds__(64) void k_head(const float* __restrict__ emb1, const float* __restrict__ cnt1,
                                             const float* __restrict__ emb2, const float* __restrict__ cnt2,
                                             const float* __restrict__ fc1W, const float* __restrict__ fc1b,
                                             const float* __restrict__ fc2W, const float* __restrict__ fc2b,
                                             float* __restrict__ out) {
    const int g = blockIdx.x;
    const int lane = threadIdx.x;
    __shared__ float comb[192];
    const float c1 = fmaxf(cnt1[g], 1.0f), c2 = fmaxf(cnt2[g], 1.0f);
    const float e1 = emb1[g * 64 + lane] / c1;
    const float e2 = emb2[g * 64 + lane] / c2;
    comb[lane] = e1;
    comb[64 + lane] = e2;
    comb[128 + lane] = fabsf(e1 - e2);
    __syncthreads();
    float acc = fc1b[lane];
    for (int k = 0; k < 192; ++k) acc += comb[k] * fc1W[k * 64 + lane];
    const float o1 = fmaxf(acc, 0.0f);
    float p = o1 * fc2W[lane];
#pragma unroll
    for (int off = 32; off > 0; off >>= 1) p += __shfl_xor(p, off);
    if (lane == 0) out[g] = 1.0f / (1.0f + expf(-(p + fc2b[0])));
}

extern "C" void kernel_launch(void* const* d_in, const int* in_sizes, int n_in,
                              void* d_out, int out_size, void* d_ws, size_t ws_size,
                              hipStream_t stream) {
    const float* x1   = (const float*)d_in[0];
    const int*   ei1  = (const int*)d_in[1];
    const int*   bt1  = (const int*)d_in[2];
    const float* x2   = (const float*)d_in[3];
    const int*   ei2  = (const int*)d_in[4];
    const int*   bt2  = (const int*)d_in[5];
    const float* W1   = (const float*)d_in[6];
    const float* bb1  = (const float*)d_in[7];
    const float* W2   = (const float*)d_in[8];
    const float* bb2  = (const float*)d_in[9];
    const float* fc1W = (const float*)d_in[10];
    const float* fc1b = (const float*)d_in[11];
    const float* fc2W = (const float*)d_in[12];
    const float* fc2b = (const float*)d_in[13];
    float* out = (float*)d_out;

    const int N = in_sizes[0] / 128;
    const int E = in_sizes[1] / 2;
    const int G = out_size;
    const int E4 = E / 4;
    const int M4b = (8 * N) / 4;
    const int NBLKb = (M4b + 255) / 256;
    const int M4d = N / 4;
    const int NBLKd = (M4d + 255) / 256;

    // 16B-aligned workspace carve-out
    char* base = (char*)d_ws;
    size_t off = 0;
    auto carve = [&](size_t bytes) {
        void* p = base + off;
        off = (off + bytes + 15) & ~(size_t)15;
        return p;
    };
    float* dinv   = (float*)carve((size_t)N * 4);
    float* emb1   = (float*)carve((size_t)G * 64 * 4);
    float* cnt1   = (float*)carve((size_t)G * 4);
    float* emb2   = (float*)carve((size_t)G * 64 * 4);
    float* cnt2   = (float*)carve((size_t)G * 4);
    int* degN     = (int*)carve((size_t)N * 4);
    int* rowstart = (int*)carve((size_t)(N + 1) * 4);
    int* bcnt     = (int*)carve((size_t)N * 8 * 4);
    int* cur      = (int*)carve((size_t)N * 8 * 4);
    int* partial  = (int*)carve(1024 * 4);
    int* col      = (int*)carve((size_t)E * 4);
    int* colN     = (int*)carve((size_t)E * 4);
    unsigned short* XWs = (unsigned short*)carve((size_t)N * 64 * 2);
    unsigned short* H1  = (unsigned short*)col;   // overlay (col dead after reorder)

    const int mmGrid = (N + 31) / 32;

    for (int br = 0; br < 2; ++br) {
        const float* X = br ? x2 : x1;
        const int* ei  = br ? ei2 : ei1;
        const int* bt  = br ? bt2 : bt1;
        float* emb = br ? emb2 : emb1;
        float* cnt = br ? cnt2 : cnt1;
        const int* srcp = ei;
        const int* dstp = ei + E;

        hipMemsetAsync(bcnt, 0, (size_t)N * 8 * 4, stream);
        k_bcnt<<<2048, 256, 0, stream>>>(dstp, bcnt, E4, E, N);
        k_deg<<<(N + 255) / 256, 256, 0, stream>>>(bcnt, degN, dinv, rowstart, N, E);
        k_scanA<<<NBLKb, 256, 0, stream>>>(bcnt, partial, M4b);
        k_scanB<<<1, 1024, 0, stream>>>(partial, NBLKb);
        k_scanC<<<NBLKb, 256, 0, stream>>>(bcnt, partial, cur, M4b);
        k_scanA<<<NBLKd, 256, 0, stream>>>(degN, partial, M4d);
        k_scanB<<<1, 1024, 0, stream>>>(partial, NBLKd);
        k_scanC<<<NBLKd, 256, 0, stream>>>(degN, partial, rowstart, M4d);
        k_bin<<<2048, 256, 0, stream>>>(srcp, dstp, cur, col, E4, E, N);
        k_reorder<<<(N * 8 + 255) / 256, 256, 0, stream>>>(col, cur, bcnt, rowstart, colN, N);

        k_mm<128, false><<<mmGrid, 256, 0, stream>>>(X, W1, dinv, XWs, N);
        k_agg4<false><<<2048, 256, 0, stream>>>(colN, rowstart, dinv,
                                                (const ushort4*)XWs, (const float4*)bb1,
                                                (ushort4*)H1, nullptr, nullptr, nullptr, N);
        k_mm<64, true><<<mmGrid, 256, 0, stream>>>(H1, W2, dinv, XWs, N);
        hipMemsetAsync(emb, 0, (size_t)(G * 64 + G) * 4, stream);   // emb,cnt adjacent
        k_agg4<true><<<2048, 256, 0, stream>>>(colN, rowstart, dinv,
                                               (const ushort4*)XWs, (const float4*)bb2,
                                               nullptr, bt, emb, cnt, N);
    }
    k_head<<<G, 64, 0, stream>>>(emb1, cnt1, emb2, cnt2, fc1W, fc1b, fc2W, fc2b, out);
}

// Round 9
// 1415.201 us; speedup vs baseline: 1.1048x; 1.1048x over previous
//
#include <hip/hip_runtime.h>
#include <hip/hip_fp16.h>
#include <cstdint>

// ---------------------------------------------------------------------------
// GCN Siamese. Class-major binning -> reorder to node-major CSR ->
// 64-lane unroll-16 gather aggregation over FP8(e4m3) tables.
//   per branch:
//     k_bcnt : count per (class=blockIdx&7, dst)  [bcnt[c*N+d]]
//     k_deg  : degN, dinv, rowstart[N]=E
//     scanA/B/C (bcnt[8N])  -> cur   (class-major claim bases)
//     scanA/B/C (degN[N])   -> rowstart (node-major CSR)
//     k_bin  : class-major claim+write col        (after: cur = segment ends)
//     k_reorder: col (class-major) -> colN (node-major rows)
//     k_mm<128>: XW8 = fp8(dinv * (X@W1))         [64B/row gather table]
//     k_agg<false>: wave/node, unroll-16 byte gathers; H1 = bf16(relu(...))
//     k_mm<64> : XW8 = fp8(dinv * (H1@W2))
//     k_agg<true>: same, epilogue pools into emb/cnt
//   head: sigmoid(relu([e1,e2,|e1-e2|]@fc1+b)@fc2+b)
// N=100000, E=3.2M, G=1024
// ---------------------------------------------------------------------------

__device__ __forceinline__ float fatomic(float* p, float v) {
    return unsafeAtomicAdd(p, v);   // hw global_atomic_add_f32
}
__device__ __forceinline__ float bf2f(unsigned short u) {
    union { unsigned int i; float f; } c; c.i = ((unsigned int)u) << 16; return c.f;
}
__device__ __forceinline__ unsigned short f2bf(float f) {
    union { float f; unsigned int i; } c; c.f = f;
    const unsigned int b = c.i;
    return (unsigned short)((b + 0x7FFF + ((b >> 16) & 1)) >> 16);   // RNE
}

// fp8 e4m3fn decode, branchless (handles subnormals via f32 denormal path):
// val = bitcast((b&0x7F)<<20) * 2^120, sign OR'd in.
__device__ __forceinline__ float fp8dec(unsigned int b) {
    const unsigned int mag = (b & 0x7Fu) << 20;
    const float f = __uint_as_float(mag) * __uint_as_float(0x7B800000u);
    const unsigned int r = __float_as_uint(f) | ((b & 0x80u) << 24);
    return __uint_as_float(r);
}

// f32 -> fp8 e4m3fn, RNE (via hw f32->f16 RNE, then 10->3 bit RNE + rebias)
__device__ __forceinline__ unsigned char fp8enc(float x) {
    const unsigned short h = __half_as_ushort(__float2half(x));
    const unsigned int s = (unsigned int)(h >> 15) << 7;
    const int e = (h >> 10) & 0x1F;
    const unsigned int m = h & 0x3FFu;
    if (e == 31) return (unsigned char)(s | 0x7E);        // inf/nan -> clamp 448
    if (e == 0) return (unsigned char)s;                  // < 2^-14 -> 0
    int E = e - 15 + 7;                                   // fp8 biased exponent
    if (E >= 16) return (unsigned char)(s | 0x7E);        // overflow -> 448
    if (E <= 0) {                                         // fp8 subnormal
        const unsigned int M = 0x400u | m;                // 1.m (11 bits)
        const int r = 16 - e;                             // 8..15
        const unsigned int q = (M + (1u << (r - 1)) - 1u + ((M >> r) & 1u)) >> r;
        return (unsigned char)(s | (q > 7u ? 8u : q));    // q==8 -> 2^-6 normal
    }
    unsigned int q = (m + 63u + ((m >> 7) & 1u)) >> 7;    // RNE drop 7 bits
    if (q == 8u) { q = 0u; ++E; if (E >= 16) return (unsigned char)(s | 0x7E); }
    return (unsigned char)(s | ((unsigned int)E << 3) | q);
}

// count per (class, dst node); class = blockIdx&7 (XCD round-robin)
__global__ void k_bcnt(const int* __restrict__ dst, int* __restrict__ bcnt,
                       int E4, int E, int Nn) {
    int i = blockIdx.x * blockDim.x + threadIdx.x;
    const int base = (blockIdx.x & 7) * Nn;
    const int stride = gridDim.x * blockDim.x;
    for (; i < E4; i += stride) {
        const int4 d = ((const int4*)dst)[i];
        atomicAdd(&bcnt[base + d.x], 1);
        atomicAdd(&bcnt[base + d.y], 1);
        atomicAdd(&bcnt[base + d.z], 1);
        atomicAdd(&bcnt[base + d.w], 1);
    }
    if (blockIdx.x == 0) {       // tail, class 0 (must match k_bin)
        const int t0 = E4 * 4;
        const int tl = E - t0;
        if ((int)threadIdx.x < tl) atomicAdd(&bcnt[dst[t0 + threadIdx.x]], 1);
    }
}

// degN[i], dinv[i]; rowstart[N] = E
__global__ __launch_bounds__(256) void k_deg(const int* __restrict__ bcnt,
                                             int* __restrict__ degN,
                                             float* __restrict__ dinv,
                                             int* __restrict__ rowstart,
                                             int Nn, int E) {
    const int i = blockIdx.x * 256 + threadIdx.x;
    if (i == 0) rowstart[Nn] = E;
    if (i >= Nn) return;
    int d = 0;
#pragma unroll
    for (int c = 0; c < 8; ++c) d += bcnt[c * Nn + i];
    degN[i] = d;
    dinv[i] = rsqrtf((float)d + 1.0f);
}

// ---- generic flat hierarchical exclusive scan (M ints, M%4==0) ------------
__global__ __launch_bounds__(256) void k_scanA(const int* __restrict__ in,
                                               int* __restrict__ partial, int M4) {
    __shared__ int sm[256];
    const int t = threadIdx.x;
    const int i4 = blockIdx.x * 256 + t;
    int s = 0;
    if (i4 < M4) {
        const int4 v = ((const int4*)in)[i4];
        s = (v.x + v.y) + (v.z + v.w);
    }
    sm[t] = s;
    __syncthreads();
    for (int off = 128; off > 0; off >>= 1) {
        if (t < off) sm[t] += sm[t + off];
        __syncthreads();
    }
    if (t == 0) partial[blockIdx.x] = sm[0];
}

__global__ __launch_bounds__(1024) void k_scanB(int* __restrict__ partial, int NBLK) {
    __shared__ int sm[1024];
    const int t = threadIdx.x;
    const int v = (t < NBLK) ? partial[t] : 0;
    sm[t] = v;
    __syncthreads();
    for (int off = 1; off < 1024; off <<= 1) {
        const int u = (t >= off) ? sm[t - off] : 0;
        __syncthreads();
        sm[t] += u;
        __syncthreads();
    }
    if (t < NBLK) partial[t] = sm[t] - v;   // exclusive
}

__global__ __launch_bounds__(256) void k_scanC(const int* __restrict__ in,
                                               const int* __restrict__ partial,
                                               int* __restrict__ outbase, int M4) {
    __shared__ int sm[256];
    const int t = threadIdx.x;
    const int i4 = blockIdx.x * 256 + t;
    int4 v = make_int4(0, 0, 0, 0);
    if (i4 < M4) v = ((const int4*)in)[i4];
    const int s = (v.x + v.y) + (v.z + v.w);
    sm[t] = s;
    __syncthreads();
    for (int off = 1; off < 256; off <<= 1) {
        const int u = (t >= off) ? sm[t - off] : 0;
        __syncthreads();
        sm[t] += u;
        __syncthreads();
    }
    if (i4 < M4) {
        int run = partial[blockIdx.x] + sm[t] - s;
        int4 w;
        w.x = run;
        w.y = w.x + v.x;
        w.z = w.y + v.y;
        w.w = w.z + v.z;
        ((int4*)outbase)[i4] = w;
    }
}

// claim + write col[pos] = src (class-major). Same mapping as k_bcnt.
__global__ void k_bin(const int* __restrict__ src, const int* __restrict__ dst,
                      int* __restrict__ cur, int* __restrict__ col,
                      int E4, int E, int Nn) {
    int i = blockIdx.x * blockDim.x + threadIdx.x;
    const int base = (blockIdx.x & 7) * Nn;
    const int stride = gridDim.x * blockDim.x;
    for (; i < E4; i += stride) {
        const int4 d = ((const int4*)dst)[i];
        const int4 sv = ((const int4*)src)[i];
        int p;
        p = atomicAdd(&cur[base + d.x], 1); col[p] = sv.x;
        p = atomicAdd(&cur[base + d.y], 1); col[p] = sv.y;
        p = atomicAdd(&cur[base + d.z], 1); col[p] = sv.z;
        p = atomicAdd(&cur[base + d.w], 1); col[p] = sv.w;
    }
    if (blockIdx.x == 0) {
        const int t0 = E4 * 4;
        const int tl = E - t0;
        if ((int)threadIdx.x < tl) {
            const int e = t0 + threadIdx.x;
            const int p = atomicAdd(&cur[dst[e]], 1);
            col[p] = src[e];
        }
    }
}

// class-major col -> node-major colN. Thread = (node i = tid>>3, class c = tid&7).
__global__ __launch_bounds__(256) void k_reorder(const int* __restrict__ col,
                                                 const int* __restrict__ cur,
                                                 const int* __restrict__ bcnt,
                                                 const int* __restrict__ rowstart,
                                                 int* __restrict__ colN, int Nn) {
    const int tid = blockIdx.x * 256 + threadIdx.x;
    if (tid >= Nn * 8) return;
    const int i = tid >> 3;
    const int c = tid & 7;
    const int L = bcnt[c * Nn + i];
    int pref = L;
#pragma unroll
    for (int d = 1; d < 8; d <<= 1) {
        const int u = __shfl_up(pref, d, 8);
        if (c >= d) pref += u;
    }
    const int off = rowstart[i] + (pref - L);
    if (L == 0) return;
    const int s0 = cur[c * Nn + i] - L;     // class-major segment start
    for (int k = 0; k < L; ++k)
        colN[off + k] = col[s0 + k];
}

// Y[row] = fp8(dinv[row] * (X@W)[row]) ; X is f32 or bf16
template <int K, bool BF16IN>
__global__ __launch_bounds__(256) void k_mm(const void* __restrict__ Xv,
                                            const float* __restrict__ W,
                                            const float* __restrict__ dinv,
                                            unsigned char* __restrict__ Y, int n) {
    __shared__ float WL[K * 64];
    __shared__ float XT[32 * K];
    const int tid = threadIdx.x;
    for (int i = tid * 4; i < K * 64; i += 1024)
        *(float4*)&WL[i] = *(const float4*)&W[i];
    const int rowBase = blockIdx.x * 32;
    const int rows = min(32, n - rowBase);
    if (BF16IN) {
        const unsigned short* xs = (const unsigned short*)Xv + (size_t)rowBase * K;
        for (int i = tid * 4; i < rows * K; i += 1024) {
            const ushort4 u = *(const ushort4*)&xs[i];
            XT[i + 0] = bf2f(u.x); XT[i + 1] = bf2f(u.y);
            XT[i + 2] = bf2f(u.z); XT[i + 3] = bf2f(u.w);
        }
    } else {
        const float* xs = (const float*)Xv + (size_t)rowBase * K;
        for (int i = tid * 4; i < rows * K; i += 1024)
            *(float4*)&XT[i] = *(const float4*)&xs[i];
    }
    __syncthreads();
    const int colf = tid & 63;
    const int rg = tid >> 6;
    float acc[8] = {};
    for (int k4 = 0; k4 < K / 4; ++k4) {
        const float w0 = WL[(k4 * 4 + 0) * 64 + colf];
        const float w1 = WL[(k4 * 4 + 1) * 64 + colf];
        const float w2 = WL[(k4 * 4 + 2) * 64 + colf];
        const float w3 = WL[(k4 * 4 + 3) * 64 + colf];
#pragma unroll
        for (int r = 0; r < 8; ++r) {
            const float4 xv = *(const float4*)&XT[(rg * 8 + r) * K + k4 * 4];
            acc[r] += xv.x * w0 + xv.y * w1 + xv.z * w2 + xv.w * w3;
        }
    }
#pragma unroll
    for (int r = 0; r < 8; ++r) {
        const int row = rowBase + rg * 8 + r;
        if (row < n) Y[(size_t)row * 64 + colf] = fp8enc(dinv[row] * acc[r]);
    }
}

// node-major CSR aggregation: wave per node, lane = feature, unroll-16,
// fp8 gather rows (64B per row).
template <bool POOL>
__global__ __launch_bounds__(256) void k_agg(const int* __restrict__ colN,
                                             const int* __restrict__ rowstart,
                                             const float* __restrict__ dinv,
                                             const unsigned char* __restrict__ XW8,
                                             const float* __restrict__ bias,
                                             unsigned short* __restrict__ Hout,
                                             const int* __restrict__ batch,
                                             float* __restrict__ emb,
                                             float* __restrict__ cnt, int Nn) {
    const int lane = threadIdx.x & 63;
    const int wid = (blockIdx.x * blockDim.x + threadIdx.x) >> 6;
    const int nw = (gridDim.x * blockDim.x) >> 6;
    const float bl = bias[lane];
    for (int i = wid; i < Nn; i += nw) {
        const int s = rowstart[i], e = rowstart[i + 1];
        float acc = 0.0f;
        int j = s;
        for (; j + 16 <= e; j += 16) {
            int c[16];
#pragma unroll
            for (int q = 0; q < 16; ++q) c[q] = colN[j + q];
            unsigned int b[16];
#pragma unroll
            for (int q = 0; q < 16; ++q) b[q] = XW8[(size_t)c[q] * 64 + lane];
            float t0 = 0.f, t1 = 0.f;
#pragma unroll
            for (int q = 0; q < 8; ++q) t0 += fp8dec(b[q]);
#pragma unroll
            for (int q = 8; q < 16; ++q) t1 += fp8dec(b[q]);
            acc += t0 + t1;
        }
        for (; j + 4 <= e; j += 4) {
            const float a0 = fp8dec(XW8[(size_t)colN[j + 0] * 64 + lane]);
            const float a1 = fp8dec(XW8[(size_t)colN[j + 1] * 64 + lane]);
            const float a2 = fp8dec(XW8[(size_t)colN[j + 2] * 64 + lane]);
            const float a3 = fp8dec(XW8[(size_t)colN[j + 3] * 64 + lane]);
            acc += (a0 + a1) + (a2 + a3);
        }
        for (; j < e; ++j)
            acc += fp8dec(XW8[(size_t)colN[j] * 64 + lane]);
        const float di = dinv[i];
        const float self = fp8dec(XW8[(size_t)i * 64 + lane]);
        const float v = fmaxf(di * (acc + self) + bl, 0.0f);
        if (POOL) {
            const int g = batch[i];
            fatomic(&emb[(size_t)g * 64 + lane], v);
            if (lane == 0) fatomic(&cnt[g], 1.0f);
        } else {
            Hout[(size_t)i * 64 + lane] = f2bf(v);
        }
    }
}

// head: emb -> [e1,e2,|e1-e2|] @ fc1 -> relu -> @ fc2 -> sigmoid
__global__ __launch_bounds__(64) void k_head(const float* __restrict__ emb1, const float* __restrict__ cnt1,
                                             const float* __restrict__ emb2, const float* __restrict__ cnt2,
                                             const float* __restrict__ fc1W, const float* __restrict__ fc1b,
                                             const float* __restrict__ fc2W, const float* __restrict__ fc2b,
                                             float* __restrict__ out) {
    const int g = blockIdx.x;
    const int lane = threadIdx.x;
    __shared__ float comb[192];
    const float c1 = fmaxf(cnt1[g], 1.0f), c2 = fmaxf(cnt2[g], 1.0f);
    const float e1 = emb1[g * 64 + lane] / c1;
    const float e2 = emb2[g * 64 + lane] / c2;
    comb[lane] = e1;
    comb[64 + lane] = e2;
    comb[128 + lane] = fabsf(e1 - e2);
    __syncthreads();
    float acc = fc1b[lane];
    for (int k = 0; k < 192; ++k) acc += comb[k] * fc1W[k * 64 + lane];
    const float o1 = fmaxf(acc, 0.0f);
    float p = o1 * fc2W[lane];
#pragma unroll
    for (int off = 32; off > 0; off >>= 1) p += __shfl_xor(p, off);
    if (lane == 0) out[g] = 1.0f / (1.0f + expf(-(p + fc2b[0])));
}

extern "C" void kernel_launch(void* const* d_in, const int* in_sizes, int n_in,
                              void* d_out, int out_size, void* d_ws, size_t ws_size,
                              hipStream_t stream) {
    const float* x1   = (const float*)d_in[0];
    const int*   ei1  = (const int*)d_in[1];
    const int*   bt1  = (const int*)d_in[2];
    const float* x2   = (const float*)d_in[3];
    const int*   ei2  = (const int*)d_in[4];
    const int*   bt2  = (const int*)d_in[5];
    const float* W1   = (const float*)d_in[6];
    const float* bb1  = (const float*)d_in[7];
    const float* W2   = (const float*)d_in[8];
    const float* bb2  = (const float*)d_in[9];
    const float* fc1W = (const float*)d_in[10];
    const float* fc1b = (const float*)d_in[11];
    const float* fc2W = (const float*)d_in[12];
    const float* fc2b = (const float*)d_in[13];
    float* out = (float*)d_out;

    const int N = in_sizes[0] / 128;
    const int E = in_sizes[1] / 2;
    const int G = out_size;
    const int E4 = E / 4;
    const int M4b = (8 * N) / 4;
    const int NBLKb = (M4b + 255) / 256;
    const int M4d = N / 4;
    const int NBLKd = (M4d + 255) / 256;

    // 16B-aligned workspace carve-out
    char* base = (char*)d_ws;
    size_t off = 0;
    auto carve = [&](size_t bytes) {
        void* p = base + off;
        off = (off + bytes + 15) & ~(size_t)15;
        return p;
    };
    float* dinv   = (float*)carve((size_t)N * 4);
    float* emb1   = (float*)carve((size_t)G * 64 * 4);
    float* cnt1   = (float*)carve((size_t)G * 4);
    float* emb2   = (float*)carve((size_t)G * 64 * 4);
    float* cnt2   = (float*)carve((size_t)G * 4);
    int* degN     = (int*)carve((size_t)N * 4);
    int* rowstart = (int*)carve((size_t)(N + 1) * 4);
    int* bcnt     = (int*)carve((size_t)N * 8 * 4);
    int* cur      = (int*)carve((size_t)N * 8 * 4);
    int* partial  = (int*)carve(1024 * 4);
    int* col      = (int*)carve((size_t)E * 4);
    int* colN     = (int*)carve((size_t)E * 4);
    unsigned char* XW8 = (unsigned char*)carve((size_t)N * 64);
    unsigned short* H1 = (unsigned short*)col;   // overlay (col dead after reorder)

    const int mmGrid = (N + 31) / 32;

    for (int br = 0; br < 2; ++br) {
        const float* X = br ? x2 : x1;
        const int* ei  = br ? ei2 : ei1;
        const int* bt  = br ? bt2 : bt1;
        float* emb = br ? emb2 : emb1;
        float* cnt = br ? cnt2 : cnt1;
        const int* srcp = ei;
        const int* dstp = ei + E;

        hipMemsetAsync(bcnt, 0, (size_t)N * 8 * 4, stream);
        k_bcnt<<<2048, 256, 0, stream>>>(dstp, bcnt, E4, E, N);
        k_deg<<<(N + 255) / 256, 256, 0, stream>>>(bcnt, degN, dinv, rowstart, N, E);
        k_scanA<<<NBLKb, 256, 0, stream>>>(bcnt, partial, M4b);
        k_scanB<<<1, 1024, 0, stream>>>(partial, NBLKb);
        k_scanC<<<NBLKb, 256, 0, stream>>>(bcnt, partial, cur, M4b);
        k_scanA<<<NBLKd, 256, 0, stream>>>(degN, partial, M4d);
        k_scanB<<<1, 1024, 0, stream>>>(partial, NBLKd);
        k_scanC<<<NBLKd, 256, 0, stream>>>(degN, partial, rowstart, M4d);
        k_bin<<<2048, 256, 0, stream>>>(srcp, dstp, cur, col, E4, E, N);
        k_reorder<<<(N * 8 + 255) / 256, 256, 0, stream>>>(col, cur, bcnt, rowstart, colN, N);

        k_mm<128, false><<<mmGrid, 256, 0, stream>>>(X, W1, dinv, XW8, N);
        k_agg<false><<<2048, 256, 0, stream>>>(colN, rowstart, dinv, XW8, bb1,
                                               H1, nullptr, nullptr, nullptr, N);
        k_mm<64, true><<<mmGrid, 256, 0, stream>>>(H1, W2, dinv, XW8, N);
        hipMemsetAsync(emb, 0, (size_t)(G * 64 + G) * 4, stream);   // emb,cnt adjacent
        k_agg<true><<<2048, 256, 0, stream>>>(colN, rowstart, dinv, XW8, bb2,
                                              nullptr, bt, emb, cnt, N);
    }
    k_head<<<G, 64, 0, stream>>>(emb1, cnt1, emb2, cnt2, fc1W, fc1b, fc2W, fc2b, out);
}

// Round 10
// 831.270 us; speedup vs baseline: 1.8808x; 1.7025x over previous
//
#include <hip/hip_runtime.h>
#include <hip/hip_fp16.h>
#include <cstdint>

// ---------------------------------------------------------------------------
// GCN Siamese. LDS-staged multisplit (dst>>8 buckets) -> per-bucket LDS
// counting sort -> node-major CSR -> unroll-16 fp8 gather aggregation.
//   per branch:
//     k_split : 14336-edge chunks; regs + LDS histogram/scan/scatter;
//               per-(chunk,bucket) claim + contiguous run copy to colBkt
//     k_gscan : scan bucket counts -> gbase; rowstart[N]=E
//     k_bsort : block per bucket; LDS counting sort by dst&255 ->
//               colN (node-major), rowstart, dinv   [dense writes]
//     k_mm<128>: XW8 = fp8(dinv * (X@W1))           [64B/row gather table]
//     k_agg<false>: wave/node, unroll-16 fp8 gathers; H1 = bf16(relu(...))
//     k_mm<64> : XW8 = fp8(dinv * (H1@W2))
//     k_agg<true>: same, epilogue pools into emb/cnt
//   head: sigmoid(relu([e1,e2,|e1-e2|]@fc1+b)@fc2+b)
// N=100000, E=3.2M, G=1024
// ---------------------------------------------------------------------------

#define NBSH 8                      // 256 nodes per bucket
#define CAPB 10240                  // per-bucket capacity (mean 8184, ~23 sigma)
#define SPLIT_T 512
#define SPLIT_EPT 28
#define SPLIT_CHUNK (SPLIT_T * SPLIT_EPT)   // 14336

__device__ __forceinline__ float fatomic(float* p, float v) {
    return unsafeAtomicAdd(p, v);   // hw global_atomic_add_f32
}
__device__ __forceinline__ float bf2f(unsigned short u) {
    union { unsigned int i; float f; } c; c.i = ((unsigned int)u) << 16; return c.f;
}
__device__ __forceinline__ unsigned short f2bf(float f) {
    union { float f; unsigned int i; } c; c.f = f;
    const unsigned int b = c.i;
    return (unsigned short)((b + 0x7FFF + ((b >> 16) & 1)) >> 16);   // RNE
}

#if defined(__has_builtin)
#if __has_builtin(__builtin_amdgcn_cvt_f32_fp8) && __has_builtin(__builtin_amdgcn_cvt_pk_fp8_f32)
#define HW_FP8 1
#endif
#endif

// fp8 e4m3 decode
__device__ __forceinline__ float fp8dec(unsigned int b) {
#ifdef HW_FP8
    return __builtin_amdgcn_cvt_f32_fp8((int)b, 0);
#else
    const unsigned int mag = (b & 0x7Fu) << 20;
    const float f = __uint_as_float(mag) * __uint_as_float(0x7B800000u);
    const unsigned int r = __float_as_uint(f) | ((b & 0x80u) << 24);
    return __uint_as_float(r);
#endif
}

// f32 -> fp8 e4m3, RNE
__device__ __forceinline__ unsigned char fp8enc(float x) {
#ifdef HW_FP8
    const int v = __builtin_amdgcn_cvt_pk_fp8_f32(x, x, 0, false);
    return (unsigned char)(v & 0xFF);
#else
    const unsigned short h = __half_as_ushort(__float2half(x));
    const unsigned int s = (unsigned int)(h >> 15) << 7;
    const int e = (h >> 10) & 0x1F;
    const unsigned int m = h & 0x3FFu;
    if (e == 31) return (unsigned char)(s | 0x7E);
    if (e == 0) return (unsigned char)s;
    int E = e - 15 + 7;
    if (E >= 16) return (unsigned char)(s | 0x7E);
    if (E <= 0) {
        const unsigned int M = 0x400u | m;
        const int r = 16 - e;
        const unsigned int q = (M + (1u << (r - 1)) - 1u + ((M >> r) & 1u)) >> r;
        return (unsigned char)(s | (q > 7u ? 8u : q));
    }
    unsigned int q = (m + 63u + ((m >> 7) & 1u)) >> 7;
    if (q == 8u) { q = 0u; ++E; if (E >= 16) return (unsigned char)(s | 0x7E); }
    return (unsigned char)(s | ((unsigned int)E << 3) | q);
#endif
}

// ---- stage 1: multisplit into 391 buckets (dst>>8), dense run writes ------
__global__ __launch_bounds__(512) void k_split(const int* __restrict__ src,
                                               const int* __restrict__ dst,
                                               int* __restrict__ gcnt,
                                               int* __restrict__ colBkt,
                                               int E, int NBUK) {
    __shared__ int out[SPLIT_CHUNK];     // 57344 B
    __shared__ int bs[513];              // exclusive prefix (bs[b+1]-bs[b]=cnt)
    __shared__ int aux[512];             // cnt -> (scan tmp) -> fill -> goff
    const int t = threadIdx.x;
    const int e0 = blockIdx.x * SPLIT_CHUNK;

    int pk[SPLIT_EPT];
    int bk[SPLIT_EPT];

    aux[t] = 0;
    __syncthreads();

#pragma unroll
    for (int k = 0; k < SPLIT_EPT; ++k) {
        const int e = e0 + t + SPLIT_T * k;          // coalesced
        if (e < E) {
            const int d = dst[e];
            const int s = src[e];
            const int b = d >> NBSH;
            pk[k] = (s << NBSH) | (d & ((1 << NBSH) - 1));
            bk[k] = b;
            atomicAdd(&aux[b], 1);
        } else {
            bk[k] = -1;
        }
    }
    __syncthreads();

    // inclusive scan of aux -> bs[1..512]
    for (int off = 1; off < 512; off <<= 1) {
        const int u = (t >= off) ? aux[t - off] : 0;
        __syncthreads();
        aux[t] += u;
        __syncthreads();
    }
    bs[t + 1] = aux[t];
    if (t == 0) bs[0] = 0;
    __syncthreads();

    aux[t] = 0;                          // fill counters
    __syncthreads();

#pragma unroll
    for (int k = 0; k < SPLIT_EPT; ++k) {
        if (bk[k] >= 0) {
            const int pos = bs[bk[k]] + atomicAdd(&aux[bk[k]], 1);
            out[pos] = pk[k];
        }
    }
    __syncthreads();

    // claim global bucket space (one atomic per non-empty bucket)
    if (t < NBUK) {
        const int L = bs[t + 1] - bs[t];
        aux[t] = (L > 0) ? atomicAdd(&gcnt[t], L) : 0;   // goff
    } else if (t < 512) {
        aux[t] = 0;
    }
    __syncthreads();

    // wave-cooperative contiguous run copies
    const int wid = t >> 6, lane = t & 63;
    for (int b = wid; b < NBUK; b += 8) {
        const int L = bs[b + 1] - bs[b];
        if (L == 0) continue;
        const int gp = aux[b];
        const size_t rb = (size_t)b * CAPB;
        for (int k = lane; k < L; k += 64) {
            const int p = gp + k;
            if (p < CAPB) colBkt[rb + p] = out[bs[b] + k];
        }
    }
}

// ---- stage 1b: scan bucket counts -> gbase ; rowstart[N] = total ----------
__global__ __launch_bounds__(512) void k_gscan(const int* __restrict__ gcnt,
                                               int* __restrict__ gbase,
                                               int* __restrict__ rowstart,
                                               int NBUK, int Nn) {
    __shared__ int sm[512];
    const int t = threadIdx.x;
    const int v = (t < NBUK) ? min(gcnt[t], CAPB) : 0;
    sm[t] = v;
    __syncthreads();
    for (int off = 1; off < 512; off <<= 1) {
        const int u = (t >= off) ? sm[t - off] : 0;
        __syncthreads();
        sm[t] += u;
        __syncthreads();
    }
    if (t < NBUK) gbase[t] = sm[t] - v;  // exclusive
    if (t == 511) rowstart[Nn] = sm[511];
}

// ---- stage 2: per-bucket LDS counting sort -> colN, rowstart, dinv --------
__global__ __launch_bounds__(256) void k_bsort(const int* __restrict__ colBkt,
                                               const int* __restrict__ gcnt,
                                               const int* __restrict__ gbase,
                                               int* __restrict__ colN,
                                               int* __restrict__ rowstart,
                                               float* __restrict__ dinv,
                                               int Nn) {
    __shared__ int in[CAPB];             // 40960 B
    __shared__ int lb[257];
    __shared__ int fill[256];
    const int b = blockIdx.x;
    const int t = threadIdx.x;
    const int L = min(gcnt[b], CAPB);
    const size_t rb = (size_t)b * CAPB;
    for (int k = t; k < L; k += 256) in[k] = colBkt[rb + k];
    fill[t] = 0;                         // histogram
    __syncthreads();
    for (int k = t; k < L; k += 256) atomicAdd(&fill[in[k] & 255], 1);
    __syncthreads();
    // inclusive scan of fill -> lb
    for (int off = 1; off < 256; off <<= 1) {
        const int u = (t >= off) ? fill[t - off] : 0;
        __syncthreads();
        fill[t] += u;
        __syncthreads();
    }
    lb[t + 1] = fill[t];
    if (t == 0) lb[0] = 0;
    __syncthreads();
    const int bb = gbase[b];
    const int node = (b << NBSH) + t;
    if (node < Nn) {
        rowstart[node] = bb + lb[t];
        dinv[node] = rsqrtf((float)(lb[t + 1] - lb[t]) + 1.0f);
    }
    fill[t] = 0;
    __syncthreads();
    for (int k = t; k < L; k += 256) {
        const int v = in[k];
        const int n = v & 255;
        const int pos = bb + lb[n] + atomicAdd(&fill[n], 1);
        colN[pos] = v >> NBSH;           // src id; writes stay in one L2 region
    }
}

// Y[row] = fp8(dinv[row] * (X@W)[row]) ; X is f32 or bf16
template <int K, bool BF16IN>
__global__ __launch_bounds__(256) void k_mm(const void* __restrict__ Xv,
                                            const float* __restrict__ W,
                                            const float* __restrict__ dinv,
                                            unsigned char* __restrict__ Y, int n) {
    __shared__ float WL[K * 64];
    __shared__ float XT[32 * K];
    const int tid = threadIdx.x;
    for (int i = tid * 4; i < K * 64; i += 1024)
        *(float4*)&WL[i] = *(const float4*)&W[i];
    const int rowBase = blockIdx.x * 32;
    const int rows = min(32, n - rowBase);
    if (BF16IN) {
        const unsigned short* xs = (const unsigned short*)Xv + (size_t)rowBase * K;
        for (int i = tid * 4; i < rows * K; i += 1024) {
            const ushort4 u = *(const ushort4*)&xs[i];
            XT[i + 0] = bf2f(u.x); XT[i + 1] = bf2f(u.y);
            XT[i + 2] = bf2f(u.z); XT[i + 3] = bf2f(u.w);
        }
    } else {
        const float* xs = (const float*)Xv + (size_t)rowBase * K;
        for (int i = tid * 4; i < rows * K; i += 1024)
            *(float4*)&XT[i] = *(const float4*)&xs[i];
    }
    __syncthreads();
    const int colf = tid & 63;
    const int rg = tid >> 6;
    float acc[8] = {};
    for (int k4 = 0; k4 < K / 4; ++k4) {
        const float w0 = WL[(k4 * 4 + 0) * 64 + colf];
        const float w1 = WL[(k4 * 4 + 1) * 64 + colf];
        const float w2 = WL[(k4 * 4 + 2) * 64 + colf];
        const float w3 = WL[(k4 * 4 + 3) * 64 + colf];
#pragma unroll
        for (int r = 0; r < 8; ++r) {
            const float4 xv = *(const float4*)&XT[(rg * 8 + r) * K + k4 * 4];
            acc[r] += xv.x * w0 + xv.y * w1 + xv.z * w2 + xv.w * w3;
        }
    }
#pragma unroll
    for (int r = 0; r < 8; ++r) {
        const int row = rowBase + rg * 8 + r;
        if (row < n) Y[(size_t)row * 64 + colf] = fp8enc(dinv[row] * acc[r]);
    }
}

// node-major CSR aggregation: wave per node, lane = feature, unroll-16, fp8 rows
template <bool POOL>
__global__ __launch_bounds__(256) void k_agg(const int* __restrict__ colN,
                                             const int* __restrict__ rowstart,
                                             const float* __restrict__ dinv,
                                             const unsigned char* __restrict__ XW8,
                                             const float* __restrict__ bias,
                                             unsigned short* __restrict__ Hout,
                                             const int* __restrict__ batch,
                                             float* __restrict__ emb,
                                             float* __restrict__ cnt, int Nn) {
    const int lane = threadIdx.x & 63;
    const int wid = (blockIdx.x * blockDim.x + threadIdx.x) >> 6;
    const int nw = (gridDim.x * blockDim.x) >> 6;
    const float bl = bias[lane];
    for (int i = wid; i < Nn; i += nw) {
        const int s = rowstart[i], e = rowstart[i + 1];
        float acc = 0.0f;
        int j = s;
        for (; j + 16 <= e; j += 16) {
            int c[16];
#pragma unroll
            for (int q = 0; q < 16; ++q) c[q] = colN[j + q];
            unsigned int b[16];
#pragma unroll
            for (int q = 0; q < 16; ++q) b[q] = XW8[(size_t)c[q] * 64 + lane];
            float t0 = 0.f, t1 = 0.f;
#pragma unroll
            for (int q = 0; q < 8; ++q) t0 += fp8dec(b[q]);
#pragma unroll
            for (int q = 8; q < 16; ++q) t1 += fp8dec(b[q]);
            acc += t0 + t1;
        }
        for (; j + 4 <= e; j += 4) {
            const float a0 = fp8dec(XW8[(size_t)colN[j + 0] * 64 + lane]);
            const float a1 = fp8dec(XW8[(size_t)colN[j + 1] * 64 + lane]);
            const float a2 = fp8dec(XW8[(size_t)colN[j + 2] * 64 + lane]);
            const float a3 = fp8dec(XW8[(size_t)colN[j + 3] * 64 + lane]);
            acc += (a0 + a1) + (a2 + a3);
        }
        for (; j < e; ++j)
            acc += fp8dec(XW8[(size_t)colN[j] * 64 + lane]);
        const float di = dinv[i];
        const float self = fp8dec(XW8[(size_t)i * 64 + lane]);
        const float v = fmaxf(di * (acc + self) + bl, 0.0f);
        if (POOL) {
            const int g = batch[i];
            fatomic(&emb[(size_t)g * 64 + lane], v);
            if (lane == 0) fatomic(&cnt[g], 1.0f);
        } else {
            Hout[(size_t)i * 64 + lane] = f2bf(v);
        }
    }
}

// head: emb -> [e1,e2,|e1-e2|] @ fc1 -> relu -> @ fc2 -> sigmoid
__global__ __launch_bounds__(64) void k_head(const float* __restrict__ emb1, const float* __restrict__ cnt1,
                                             const float* __restrict__ emb2, const float* __restrict__ cnt2,
                                             const float* __restrict__ fc1W, const float* __restrict__ fc1b,
                                             const float* __restrict__ fc2W, const float* __restrict__ fc2b,
                                             float* __restrict__ out) {
    const int g = blockIdx.x;
    const int lane = threadIdx.x;
    __shared__ float comb[192];
    const float c1 = fmaxf(cnt1[g], 1.0f), c2 = fmaxf(cnt2[g], 1.0f);
    const float e1 = emb1[g * 64 + lane] / c1;
    const float e2 = emb2[g * 64 + lane] / c2;
    comb[lane] = e1;
    comb[64 + lane] = e2;
    comb[128 + lane] = fabsf(e1 - e2);
    __syncthreads();
    float acc = fc1b[lane];
    for (int k = 0; k < 192; ++k) acc += comb[k] * fc1W[k * 64 + lane];
    const float o1 = fmaxf(acc, 0.0f);
    float p = o1 * fc2W[lane];
#pragma unroll
    for (int off = 32; off > 0; off >>= 1) p += __shfl_xor(p, off);
    if (lane == 0) out[g] = 1.0f / (1.0f + expf(-(p + fc2b[0])));
}

extern "C" void kernel_launch(void* const* d_in, const int* in_sizes, int n_in,
                              void* d_out, int out_size, void* d_ws, size_t ws_size,
                              hipStream_t stream) {
    const float* x1   = (const float*)d_in[0];
    const int*   ei1  = (const int*)d_in[1];
    const int*   bt1  = (const int*)d_in[2];
    const float* x2   = (const float*)d_in[3];
    const int*   ei2  = (const int*)d_in[4];
    const int*   bt2  = (const int*)d_in[5];
    const float* W1   = (const float*)d_in[6];
    const float* bb1  = (const float*)d_in[7];
    const float* W2   = (const float*)d_in[8];
    const float* bb2  = (const float*)d_in[9];
    const float* fc1W = (const float*)d_in[10];
    const float* fc1b = (const float*)d_in[11];
    const float* fc2W = (const float*)d_in[12];
    const float* fc2b = (const float*)d_in[13];
    float* out = (float*)d_out;

    const int N = in_sizes[0] / 128;
    const int E = in_sizes[1] / 2;
    const int G = out_size;
    const int NBUK = (N + 255) >> NBSH;              // 391
    const int nchunks = (E + SPLIT_CHUNK - 1) / SPLIT_CHUNK;

    // 16B-aligned workspace carve-out
    char* base = (char*)d_ws;
    size_t off = 0;
    auto carve = [&](size_t bytes) {
        void* p = base + off;
        off = (off + bytes + 15) & ~(size_t)15;
        return p;
    };
    float* dinv   = (float*)carve((size_t)N * 4);
    float* emb1   = (float*)carve((size_t)G * 64 * 4);
    float* cnt1   = (float*)carve((size_t)G * 4);
    float* emb2   = (float*)carve((size_t)G * 64 * 4);
    float* cnt2   = (float*)carve((size_t)G * 4);
    int* rowstart = (int*)carve((size_t)(N + 1) * 4);
    int* gcnt     = (int*)carve(512 * 4);
    int* gbase    = (int*)carve(512 * 4);
    int* colBkt   = (int*)carve((size_t)NBUK * CAPB * 4);   // 16.0 MB
    int* colN     = (int*)carve((size_t)E * 4);             // 12.8 MB
    unsigned char* XW8 = (unsigned char*)carve((size_t)N * 64);
    unsigned short* H1 = (unsigned short*)colBkt;   // overlay (dead after bsort)

    const int mmGrid = (N + 31) / 32;

    for (int br = 0; br < 2; ++br) {
        const float* X = br ? x2 : x1;
        const int* ei  = br ? ei2 : ei1;
        const int* bt  = br ? bt2 : bt1;
        float* emb = br ? emb2 : emb1;
        float* cnt = br ? cnt2 : cnt1;
        const int* srcp = ei;
        const int* dstp = ei + E;

        hipMemsetAsync(gcnt, 0, 512 * 4, stream);
        k_split<<<nchunks, SPLIT_T, 0, stream>>>(srcp, dstp, gcnt, colBkt, E, NBUK);
        k_gscan<<<1, 512, 0, stream>>>(gcnt, gbase, rowstart, NBUK, N);
        k_bsort<<<NBUK, 256, 0, stream>>>(colBkt, gcnt, gbase, colN, rowstart, dinv, N);

        k_mm<128, false><<<mmGrid, 256, 0, stream>>>(X, W1, dinv, XW8, N);
        k_agg<false><<<2048, 256, 0, stream>>>(colN, rowstart, dinv, XW8, bb1,
                                               H1, nullptr, nullptr, nullptr, N);
        k_mm<64, true><<<mmGrid, 256, 0, stream>>>(H1, W2, dinv, XW8, N);
        hipMemsetAsync(emb, 0, (size_t)(G * 64 + G) * 4, stream);   // emb,cnt adjacent
        k_agg<true><<<2048, 256, 0, stream>>>(colN, rowstart, dinv, XW8, bb2,
                                              nullptr, bt, emb, cnt, N);
    }
    k_head<<<G, 64, 0, stream>>>(emb1, cnt1, emb2, cnt2, fc1W, fc1b, fc2W, fc2b, out);
}

// Round 11
// 816.527 us; speedup vs baseline: 1.9148x; 1.0181x over previous
//
#include <hip/hip_runtime.h>
#include <hip/hip_fp16.h>
#include <cstdint>

// ---------------------------------------------------------------------------
// GCN Siamese. LDS-staged multisplit (dst>>8 buckets) -> per-bucket LDS
// counting sort -> node-major CSR -> unroll-16 fp8 gather aggregation.
// r11: NT loads/stores for single-use streams (colN, H1) to keep the fp8
//      gather table L2-resident; k_mm register-pressure fix.
// N=100000, E=3.2M, G=1024
// ---------------------------------------------------------------------------

#define NBSH 8                      // 256 nodes per bucket
#define CAPB 10240                  // per-bucket capacity (mean 8184, ~23 sigma)
#define SPLIT_T 512
#define SPLIT_EPT 28
#define SPLIT_CHUNK (SPLIT_T * SPLIT_EPT)   // 14336

__device__ __forceinline__ float fatomic(float* p, float v) {
    return unsafeAtomicAdd(p, v);   // hw global_atomic_add_f32
}
__device__ __forceinline__ float bf2f(unsigned short u) {
    union { unsigned int i; float f; } c; c.i = ((unsigned int)u) << 16; return c.f;
}
__device__ __forceinline__ unsigned short f2bf(float f) {
    union { float f; unsigned int i; } c; c.f = f;
    const unsigned int b = c.i;
    return (unsigned short)((b + 0x7FFF + ((b >> 16) & 1)) >> 16);   // RNE
}

#if defined(__has_builtin)
#if __has_builtin(__builtin_amdgcn_cvt_f32_fp8) && __has_builtin(__builtin_amdgcn_cvt_pk_fp8_f32)
#define HW_FP8 1
#endif
#endif

// fp8 e4m3 decode
__device__ __forceinline__ float fp8dec(unsigned int b) {
#ifdef HW_FP8
    return __builtin_amdgcn_cvt_f32_fp8((int)b, 0);
#else
    const unsigned int mag = (b & 0x7Fu) << 20;
    const float f = __uint_as_float(mag) * __uint_as_float(0x7B800000u);
    const unsigned int r = __float_as_uint(f) | ((b & 0x80u) << 24);
    return __uint_as_float(r);
#endif
}

// f32 -> fp8 e4m3, RNE
__device__ __forceinline__ unsigned char fp8enc(float x) {
#ifdef HW_FP8
    const int v = __builtin_amdgcn_cvt_pk_fp8_f32(x, x, 0, false);
    return (unsigned char)(v & 0xFF);
#else
    const unsigned short h = __half_as_ushort(__float2half(x));
    const unsigned int s = (unsigned int)(h >> 15) << 7;
    const int e = (h >> 10) & 0x1F;
    const unsigned int m = h & 0x3FFu;
    if (e == 31) return (unsigned char)(s | 0x7E);
    if (e == 0) return (unsigned char)s;
    int E = e - 15 + 7;
    if (E >= 16) return (unsigned char)(s | 0x7E);
    if (E <= 0) {
        const unsigned int M = 0x400u | m;
        const int r = 16 - e;
        const unsigned int q = (M + (1u << (r - 1)) - 1u + ((M >> r) & 1u)) >> r;
        return (unsigned char)(s | (q > 7u ? 8u : q));
    }
    unsigned int q = (m + 63u + ((m >> 7) & 1u)) >> 7;
    if (q == 8u) { q = 0u; ++E; if (E >= 16) return (unsigned char)(s | 0x7E); }
    return (unsigned char)(s | ((unsigned int)E << 3) | q);
#endif
}

// ---- stage 1: multisplit into 391 buckets (dst>>8), dense run writes ------
__global__ __launch_bounds__(512) void k_split(const int* __restrict__ src,
                                               const int* __restrict__ dst,
                                               int* __restrict__ gcnt,
                                               int* __restrict__ colBkt,
                                               int E, int NBUK) {
    __shared__ int out[SPLIT_CHUNK];     // 57344 B
    __shared__ int bs[513];
    __shared__ int aux[512];
    const int t = threadIdx.x;
    const int e0 = blockIdx.x * SPLIT_CHUNK;

    int pk[SPLIT_EPT];
    int bk[SPLIT_EPT];

    aux[t] = 0;
    __syncthreads();

#pragma unroll
    for (int k = 0; k < SPLIT_EPT; ++k) {
        const int e = e0 + t + SPLIT_T * k;          // coalesced
        if (e < E) {
            const int d = dst[e];
            const int s = src[e];
            const int b = d >> NBSH;
            pk[k] = (s << NBSH) | (d & ((1 << NBSH) - 1));
            bk[k] = b;
            atomicAdd(&aux[b], 1);
        } else {
            bk[k] = -1;
        }
    }
    __syncthreads();

    for (int off = 1; off < 512; off <<= 1) {
        const int u = (t >= off) ? aux[t - off] : 0;
        __syncthreads();
        aux[t] += u;
        __syncthreads();
    }
    bs[t + 1] = aux[t];
    if (t == 0) bs[0] = 0;
    __syncthreads();

    aux[t] = 0;
    __syncthreads();

#pragma unroll
    for (int k = 0; k < SPLIT_EPT; ++k) {
        if (bk[k] >= 0) {
            const int pos = bs[bk[k]] + atomicAdd(&aux[bk[k]], 1);
            out[pos] = pk[k];
        }
    }
    __syncthreads();

    if (t < NBUK) {
        const int L = bs[t + 1] - bs[t];
        aux[t] = (L > 0) ? atomicAdd(&gcnt[t], L) : 0;   // goff
    } else if (t < 512) {
        aux[t] = 0;
    }
    __syncthreads();

    const int wid = t >> 6, lane = t & 63;
    for (int b = wid; b < NBUK; b += 8) {
        const int L = bs[b + 1] - bs[b];
        if (L == 0) continue;
        const int gp = aux[b];
        const size_t rb = (size_t)b * CAPB;
        for (int k = lane; k < L; k += 64) {
            const int p = gp + k;
            if (p < CAPB) colBkt[rb + p] = out[bs[b] + k];
        }
    }
}

// ---- stage 1b: scan bucket counts -> gbase ; rowstart[N] = total ----------
__global__ __launch_bounds__(512) void k_gscan(const int* __restrict__ gcnt,
                                               int* __restrict__ gbase,
                                               int* __restrict__ rowstart,
                                               int NBUK, int Nn) {
    __shared__ int sm[512];
    const int t = threadIdx.x;
    const int v = (t < NBUK) ? min(gcnt[t], CAPB) : 0;
    sm[t] = v;
    __syncthreads();
    for (int off = 1; off < 512; off <<= 1) {
        const int u = (t >= off) ? sm[t - off] : 0;
        __syncthreads();
        sm[t] += u;
        __syncthreads();
    }
    if (t < NBUK) gbase[t] = sm[t] - v;  // exclusive
    if (t == 511) rowstart[Nn] = sm[511];
}

// ---- stage 2: per-bucket LDS counting sort -> colN, rowstart, dinv --------
__global__ __launch_bounds__(256) void k_bsort(const int* __restrict__ colBkt,
                                               const int* __restrict__ gcnt,
                                               const int* __restrict__ gbase,
                                               int* __restrict__ colN,
                                               int* __restrict__ rowstart,
                                               float* __restrict__ dinv,
                                               int Nn) {
    __shared__ int in[CAPB];             // 40960 B
    __shared__ int lb[257];
    __shared__ int fill[256];
    const int b = blockIdx.x;
    const int t = threadIdx.x;
    const int L = min(gcnt[b], CAPB);
    const size_t rb = (size_t)b * CAPB;
    for (int k = t; k < L; k += 256) in[k] = colBkt[rb + k];
    fill[t] = 0;
    __syncthreads();
    for (int k = t; k < L; k += 256) atomicAdd(&fill[in[k] & 255], 1);
    __syncthreads();
    for (int off = 1; off < 256; off <<= 1) {
        const int u = (t >= off) ? fill[t - off] : 0;
        __syncthreads();
        fill[t] += u;
        __syncthreads();
    }
    lb[t + 1] = fill[t];
    if (t == 0) lb[0] = 0;
    __syncthreads();
    const int bb = gbase[b];
    const int node = (b << NBSH) + t;
    if (node < Nn) {
        rowstart[node] = bb + lb[t];
        dinv[node] = rsqrtf((float)(lb[t + 1] - lb[t]) + 1.0f);
    }
    fill[t] = 0;
    __syncthreads();
    for (int k = t; k < L; k += 256) {
        const int v = in[k];
        const int n = v & 255;
        const int pos = bb + lb[n] + atomicAdd(&fill[n], 1);
        colN[pos] = v >> NBSH;
    }
}

// Y[row] = fp8(dinv[row] * (X@W)[row]) ; X is f32 or bf16
// launch_bounds(256,4): cap VGPR at 128 (r10 had 256 VGPR -> 0.5% occupancy)
template <int K, bool BF16IN>
__global__ __launch_bounds__(256, 4) void k_mm(const void* __restrict__ Xv,
                                               const float* __restrict__ W,
                                               const float* __restrict__ dinv,
                                               unsigned char* __restrict__ Y, int n) {
    __shared__ float WL[K * 64];
    __shared__ float XT[32 * K];
    const int tid = threadIdx.x;
    for (int i = tid * 4; i < K * 64; i += 1024)
        *(float4*)&WL[i] = *(const float4*)&W[i];
    const int rowBase = blockIdx.x * 32;
    const int rows = min(32, n - rowBase);
    if (BF16IN) {
        const unsigned short* xs = (const unsigned short*)Xv + (size_t)rowBase * K;
        for (int i = tid * 4; i < rows * K; i += 1024) {
            const ushort4 u = *(const ushort4*)&xs[i];
            XT[i + 0] = bf2f(u.x); XT[i + 1] = bf2f(u.y);
            XT[i + 2] = bf2f(u.z); XT[i + 3] = bf2f(u.w);
        }
    } else {
        const float* xs = (const float*)Xv + (size_t)rowBase * K;
        for (int i = tid * 4; i < rows * K; i += 1024)
            *(float4*)&XT[i] = *(const float4*)&xs[i];
    }
    __syncthreads();
    const int colf = tid & 63;
    const int rg = tid >> 6;
    float acc[8] = {};
#pragma unroll 4
    for (int k4 = 0; k4 < K / 4; ++k4) {
        const float w0 = WL[(k4 * 4 + 0) * 64 + colf];
        const float w1 = WL[(k4 * 4 + 1) * 64 + colf];
        const float w2 = WL[(k4 * 4 + 2) * 64 + colf];
        const float w3 = WL[(k4 * 4 + 3) * 64 + colf];
#pragma unroll
        for (int r = 0; r < 8; ++r) {
            const float4 xv = *(const float4*)&XT[(rg * 8 + r) * K + k4 * 4];
            acc[r] += xv.x * w0 + xv.y * w1 + xv.z * w2 + xv.w * w3;
        }
    }
#pragma unroll
    for (int r = 0; r < 8; ++r) {
        const int row = rowBase + rg * 8 + r;
        if (row < n)
            __builtin_nontemporal_store(fp8enc(dinv[row] * acc[r]),
                                        &Y[(size_t)row * 64 + colf]);
    }
}

// node-major CSR aggregation: wave per node, lane = feature, unroll-16, fp8 rows.
// colN reads + H1 writes are non-temporal (single-use streams) -> keep the
// 6.4MB fp8 table L2-resident.
template <bool POOL>
__global__ __launch_bounds__(256) void k_agg(const int* __restrict__ colN,
                                             const int* __restrict__ rowstart,
                                             const float* __restrict__ dinv,
                                             const unsigned char* __restrict__ XW8,
                                             const float* __restrict__ bias,
                                             unsigned short* __restrict__ Hout,
                                             const int* __restrict__ batch,
                                             float* __restrict__ emb,
                                             float* __restrict__ cnt, int Nn) {
    const int lane = threadIdx.x & 63;
    const int wid = (blockIdx.x * blockDim.x + threadIdx.x) >> 6;
    const int nw = (gridDim.x * blockDim.x) >> 6;
    const float bl = bias[lane];
    for (int i = wid; i < Nn; i += nw) {
        const int s = rowstart[i], e = rowstart[i + 1];
        float acc = 0.0f;
        int j = s;
        for (; j + 16 <= e; j += 16) {
            int c[16];
#pragma unroll
            for (int q = 0; q < 16; ++q) c[q] = __builtin_nontemporal_load(&colN[j + q]);
            unsigned int b[16];
#pragma unroll
            for (int q = 0; q < 16; ++q) b[q] = XW8[(size_t)c[q] * 64 + lane];
            float t0 = 0.f, t1 = 0.f;
#pragma unroll
            for (int q = 0; q < 8; ++q) t0 += fp8dec(b[q]);
#pragma unroll
            for (int q = 8; q < 16; ++q) t1 += fp8dec(b[q]);
            acc += t0 + t1;
        }
        for (; j + 4 <= e; j += 4) {
            const int c0 = __builtin_nontemporal_load(&colN[j + 0]);
            const int c1 = __builtin_nontemporal_load(&colN[j + 1]);
            const int c2 = __builtin_nontemporal_load(&colN[j + 2]);
            const int c3 = __builtin_nontemporal_load(&colN[j + 3]);
            const float a0 = fp8dec(XW8[(size_t)c0 * 64 + lane]);
            const float a1 = fp8dec(XW8[(size_t)c1 * 64 + lane]);
            const float a2 = fp8dec(XW8[(size_t)c2 * 64 + lane]);
            const float a3 = fp8dec(XW8[(size_t)c3 * 64 + lane]);
            acc += (a0 + a1) + (a2 + a3);
        }
        for (; j < e; ++j) {
            const int c0 = __builtin_nontemporal_load(&colN[j]);
            acc += fp8dec(XW8[(size_t)c0 * 64 + lane]);
        }
        const float di = dinv[i];
        const float self = fp8dec(XW8[(size_t)i * 64 + lane]);
        const float v = fmaxf(di * (acc + self) + bl, 0.0f);
        if (POOL) {
            const int g = batch[i];
            fatomic(&emb[(size_t)g * 64 + lane], v);
            if (lane == 0) fatomic(&cnt[g], 1.0f);
        } else {
            __builtin_nontemporal_store(f2bf(v), &Hout[(size_t)i * 64 + lane]);
        }
    }
}

// head: emb -> [e1,e2,|e1-e2|] @ fc1 -> relu -> @ fc2 -> sigmoid
__global__ __launch_bounds__(64) void k_head(const float* __restrict__ emb1, const float* __restrict__ cnt1,
                                             const float* __restrict__ emb2, const float* __restrict__ cnt2,
                                             const float* __restrict__ fc1W, const float* __restrict__ fc1b,
                                             const float* __restrict__ fc2W, const float* __restrict__ fc2b,
                                             float* __restrict__ out) {
    const int g = blockIdx.x;
    const int lane = threadIdx.x;
    __shared__ float comb[192];
    const float c1 = fmaxf(cnt1[g], 1.0f), c2 = fmaxf(cnt2[g], 1.0f);
    const float e1 = emb1[g * 64 + lane] / c1;
    const float e2 = emb2[g * 64 + lane] / c2;
    comb[lane] = e1;
    comb[64 + lane] = e2;
    comb[128 + lane] = fabsf(e1 - e2);
    __syncthreads();
    float acc = fc1b[lane];
    for (int k = 0; k < 192; ++k) acc += comb[k] * fc1W[k * 64 + lane];
    const float o1 = fmaxf(acc, 0.0f);
    float p = o1 * fc2W[lane];
#pragma unroll
    for (int off = 32; off > 0; off >>= 1) p += __shfl_xor(p, off);
    if (lane == 0) out[g] = 1.0f / (1.0f + expf(-(p + fc2b[0])));
}

extern "C" void kernel_launch(void* const* d_in, const int* in_sizes, int n_in,
                              void* d_out, int out_size, void* d_ws, size_t ws_size,
                              hipStream_t stream) {
    const float* x1   = (const float*)d_in[0];
    const int*   ei1  = (const int*)d_in[1];
    const int*   bt1  = (const int*)d_in[2];
    const float* x2   = (const float*)d_in[3];
    const int*   ei2  = (const int*)d_in[4];
    const int*   bt2  = (const int*)d_in[5];
    const float* W1   = (const float*)d_in[6];
    const float* bb1  = (const float*)d_in[7];
    const float* W2   = (const float*)d_in[8];
    const float* bb2  = (const float*)d_in[9];
    const float* fc1W = (const float*)d_in[10];
    const float* fc1b = (const float*)d_in[11];
    const float* fc2W = (const float*)d_in[12];
    const float* fc2b = (const float*)d_in[13];
    float* out = (float*)d_out;

    const int N = in_sizes[0] / 128;
    const int E = in_sizes[1] / 2;
    const int G = out_size;
    const int NBUK = (N + 255) >> NBSH;              // 391
    const int nchunks = (E + SPLIT_CHUNK - 1) / SPLIT_CHUNK;

    // 16B-aligned workspace carve-out
    char* base = (char*)d_ws;
    size_t off = 0;
    auto carve = [&](size_t bytes) {
        void* p = base + off;
        off = (off + bytes + 15) & ~(size_t)15;
        return p;
    };
    float* dinv   = (float*)carve((size_t)N * 4);
    float* emb1   = (float*)carve((size_t)G * 64 * 4);
    float* cnt1   = (float*)carve((size_t)G * 4);
    float* emb2   = (float*)carve((size_t)G * 64 * 4);
    float* cnt2   = (float*)carve((size_t)G * 4);
    int* rowstart = (int*)carve((size_t)(N + 1) * 4);
    int* gcnt     = (int*)carve(512 * 4);
    int* gbase    = (int*)carve(512 * 4);
    int* colBkt   = (int*)carve((size_t)NBUK * CAPB * 4);   // 16.0 MB
    int* colN     = (int*)carve((size_t)E * 4);             // 12.8 MB
    unsigned char* XW8 = (unsigned char*)carve((size_t)N * 64);
    unsigned short* H1 = (unsigned short*)colBkt;   // overlay (dead after bsort)

    const int mmGrid = (N + 31) / 32;

    for (int br = 0; br < 2; ++br) {
        const float* X = br ? x2 : x1;
        const int* ei  = br ? ei2 : ei1;
        const int* bt  = br ? bt2 : bt1;
        float* emb = br ? emb2 : emb1;
        float* cnt = br ? cnt2 : cnt1;
        const int* srcp = ei;
        const int* dstp = ei + E;

        hipMemsetAsync(gcnt, 0, 512 * 4, stream);
        k_split<<<nchunks, SPLIT_T, 0, stream>>>(srcp, dstp, gcnt, colBkt, E, NBUK);
        k_gscan<<<1, 512, 0, stream>>>(gcnt, gbase, rowstart, NBUK, N);
        k_bsort<<<NBUK, 256, 0, stream>>>(colBkt, gcnt, gbase, colN, rowstart, dinv, N);

        k_mm<128, false><<<mmGrid, 256, 0, stream>>>(X, W1, dinv, XW8, N);
        k_agg<false><<<2048, 256, 0, stream>>>(colN, rowstart, dinv, XW8, bb1,
                                               H1, nullptr, nullptr, nullptr, N);
        k_mm<64, true><<<mmGrid, 256, 0, stream>>>(H1, W2, dinv, XW8, N);
        hipMemsetAsync(emb, 0, (size_t)(G * 64 + G) * 4, stream);   // emb,cnt adjacent
        k_agg<true><<<2048, 256, 0, stream>>>(colN, rowstart, dinv, XW8, bb2,
                                              nullptr, bt, emb, cnt, N);
    }
    k_head<<<G, 64, 0, stream>>>(emb1, cnt1, emb2, cnt2, fc1W, fc1b, fc2W, fc2b, out);
}